// Round 5
// baseline (510.003 us; speedup 1.0000x reference)
//
#include <hip/hip_runtime.h>
#include <hip/hip_bf16.h>
#include <math.h>

// Shapes (compile-time constants from the reference)
constexpr int kB = 8;
constexpr int kT = 16;
constexpr int kN = 1024;
constexpr int kH = 128;
constexpr int kSNP = 4;
constexpr int kNT = kSNP * kN;          // 4096
constexpr int kRows = kB * kNT;         // 32768 GEMM rows
constexpr int kSeqOut = 12;
constexpr float kLRelu = 0.2f;
// Edge layout constants (structure of _build_edges; src VALUES read from input)
constexpr int kEdgePerSnap = kN * 8 + kN;   // 9216
constexpr int kSelfOff = kN * 8;            // 8192
constexpr int kTempBase = kSNP * kEdgePerSnap; // 36864
// stats layout: [iter][b][slot(16)][16] floats -> per-(b,slot) 64-B line
constexpr int kStatsPerIter = kB * 16 * 16; // 2048 floats

typedef __bf16 bf16x8 __attribute__((ext_vector_type(8)));
typedef float f32x4 __attribute__((ext_vector_type(4)));

// ---------------------------------------------------------------------------
// prep_w: split gw0/gw1 fp32 -> bf16 hi/lo in MFMA fragment layout.
// Layout: buf[((s*4+q)*128 + col)*8 + j] holds W[(s*32+q*8+j)*128 + col]
// (s = K-step 0..3, q = lane>>4, j = element 0..7). 16B-contiguous per frag.
// ---------------------------------------------------------------------------
__global__ void prep_w(const float* __restrict__ gw0, const float* __restrict__ gw1,
                       unsigned short* __restrict__ wbuf) {
  int tid = blockIdx.x * 256 + threadIdx.x;   // 0 .. 32767 (2 layers x 16384)
  int layer = tid >> 14;
  int e = tid & 16383;
  int k = e >> 7, col = e & 127;
  const float* W = layer ? gw1 : gw0;
  float w = W[k * kH + col];
  unsigned int bits = __float_as_uint(w);
  unsigned short hi = (unsigned short)(bits >> 16);
  float hif = __uint_as_float(bits & 0xffff0000u);
  unsigned short lo = (unsigned short)(__float_as_uint(w - hif) >> 16);
  int s = k >> 5, q = (k >> 3) & 3, j = k & 7;
  int off = ((s * 4 + q) * kH + col) * 8 + j;
  wbuf[layer * 32768 + off] = hi;
  wbuf[layer * 32768 + 16384 + off] = lo;
}

// ---------------------------------------------------------------------------
// Window build: A[b][t'][n][h] = (t'==0 && !first) ? LN(last) : x[b,tg,n,h]
// x recomputed on the fly. XCD-swizzled: batch b -> XCD b (b = blockIdx & 7).
// ---------------------------------------------------------------------------
__global__ void build_fs(const float* __restrict__ inputs, const float* __restrict__ W_in,
                         const float* __restrict__ b_in, const float* __restrict__ spatial,
                         const float* __restrict__ temporal, const float* __restrict__ last,
                         const float* __restrict__ stats, float* __restrict__ A,
                         int left, int first) {
  int blk = blockIdx.x;                 // 4096 blocks; 512 per batch
  int b = blk & 7;
  int inner = blk >> 3;                 // 0..511
  int idx4 = (b << 17) | (inner << 8) | threadIdx.x;  // over B*4*N*(H/4)
  int h4 = idx4 & 31;
  int n  = (idx4 >> 5) & 1023;
  int t  = (idx4 >> 15) & 3;
  float4 out;
  if (!first && t == 0) {
    float s1 = 0.f, s2 = 0.f;
    #pragma unroll
    for (int s = 0; s < 16; ++s) {
      s1 += stats[b * 256 + s * 16];
      s2 += stats[b * 256 + s * 16 + 1];
    }
    const float inv = 1.0f / (float)(kN * kH);
    float mu = s1 * inv;
    float var = s2 * inv - mu * mu;
    float sc = rsqrtf(var + 1e-5f);
    float4 v = *(const float4*)(last + ((size_t)(b * kN + n)) * kH + h4 * 4);
    out.x = (v.x - mu) * sc; out.y = (v.y - mu) * sc;
    out.z = (v.z - mu) * sc; out.w = (v.w - mu) * sc;
  } else {
    int tg = left + t - (first ? 0 : 1);
    float2 iv = *(const float2*)(inputs + ((size_t)((b * kT + tg) * kN + n)) * 2);
    float tv = temporal[n * kT + tg];
    float4 w0 = *(const float4*)(W_in + h4 * 4);
    float4 w1 = *(const float4*)(W_in + kH + h4 * 4);
    float4 bb = *(const float4*)(b_in + h4 * 4);
    float4 sp = *(const float4*)(spatial + n * kH + h4 * 4);
    out.x = iv.x * w0.x + iv.y * w1.x + bb.x + sp.x + tv;
    out.y = iv.x * w0.y + iv.y * w1.y + bb.y + sp.y + tv;
    out.z = iv.x * w0.z + iv.y * w1.z + bb.z + sp.z + tv;
    out.w = iv.x * w0.w + iv.y * w1.w + bb.w + sp.w + tv;
  }
  *(float4*)(A + (size_t)idx4 * 4) = out;
}

// ---------------------------------------------------------------------------
// Split-bf16 MFMA GEMM + fused el/er epilogue.
// Out[M,128] = In[M,128] @ W[128,128]  (fp32-accurate via Ah@Wh+Al@Wh+Ah@Wl)
// W hi/lo pre-split into fragment layout by prep_w (16B vector loads).
// XCD-swizzled: batch b (64 row-blocks of 64) -> XCD b.
// ---------------------------------------------------------------------------
__launch_bounds__(256)
__global__ void gemm_mfma(const float* __restrict__ In, const unsigned short* __restrict__ Wh,
                          const unsigned short* __restrict__ Wl,
                          const float* __restrict__ gal, const float* __restrict__ gar,
                          float* __restrict__ Out, float* __restrict__ elp,
                          float* __restrict__ erp) {
  __shared__ unsigned short AhL[64 * 128];   // 16 KB, swizzled bf16 hi
  __shared__ unsigned short AlL[64 * 128];   // 16 KB, swizzled bf16 lo
  int tid = threadIdx.x;
  int lane = tid & 63, wid = tid >> 6;
  int blk = blockIdx.x;            // 512 blocks; 64 per batch
  int rowblk = ((blk & 7) << 6) | (blk >> 3);
  int blockRow0 = rowblk * 64;
  int colL = lane & 15;
  int q = lane >> 4;

  // ---- W fragments (pre-split, vector loads) ----
  bf16x8 bh[2][4], bl[2][4];
  #pragma unroll
  for (int c = 0; c < 2; ++c) {
    int col = wid * 32 + c * 16 + colL;
    #pragma unroll
    for (int s = 0; s < 4; ++s) {
      int off = ((s * 4 + q) * kH + col) * 8;
      bh[c][s] = *(const bf16x8*)(Wh + off);
      bl[c][s] = *(const bf16x8*)(Wl + off);
    }
  }

  // ---- Stage A tile (64x128 fp32) -> LDS bf16 hi/lo, swizzled ----
  const float* Ablk = In + (size_t)blockRow0 * kH;
  #pragma unroll
  for (int itn = 0; itn < 8; ++itn) {
    int fid = itn * 256 + tid;
    int row = fid >> 5, kq = fid & 31;     // 32 float4 per row
    float4 v = *(const float4*)(Ablk + (size_t)row * kH + kq * 4);
    ushort4 hi, lo;
    unsigned int bx = __float_as_uint(v.x);
    hi.x = bx >> 16; lo.x = __float_as_uint(v.x - __uint_as_float(bx & 0xffff0000u)) >> 16;
    unsigned int by = __float_as_uint(v.y);
    hi.y = by >> 16; lo.y = __float_as_uint(v.y - __uint_as_float(by & 0xffff0000u)) >> 16;
    unsigned int bz = __float_as_uint(v.z);
    hi.z = bz >> 16; lo.z = __float_as_uint(v.z - __uint_as_float(bz & 0xffff0000u)) >> 16;
    unsigned int bw = __float_as_uint(v.w);
    hi.w = bw >> 16; lo.w = __float_as_uint(v.w - __uint_as_float(bw & 0xffff0000u)) >> 16;
    int boff = (row * 256 + kq * 8) ^ ((row & 7) << 4);
    *(ushort4*)((char*)AhL + boff) = hi;
    *(ushort4*)((char*)AlL + boff) = lo;
  }
  __syncthreads();

  // ---- MFMA main loop: K = 4 steps of 32 ----
  f32x4 acc[4][2];
  #pragma unroll
  for (int rb = 0; rb < 4; ++rb)
    #pragma unroll
    for (int c = 0; c < 2; ++c) acc[rb][c] = (f32x4){0.f, 0.f, 0.f, 0.f};

  #pragma unroll
  for (int s = 0; s < 4; ++s) {
    bf16x8 ah[4], alr[4];
    #pragma unroll
    for (int rb = 0; rb < 4; ++rb) {
      int row = rb * 16 + colL;
      int boff = (row * 256 + s * 64 + q * 16) ^ ((row & 7) << 4);
      ah[rb]  = *(const bf16x8*)((const char*)AhL + boff);
      alr[rb] = *(const bf16x8*)((const char*)AlL + boff);
    }
    #pragma unroll
    for (int c = 0; c < 2; ++c) {
      #pragma unroll
      for (int rb = 0; rb < 4; ++rb)
        acc[rb][c] = __builtin_amdgcn_mfma_f32_16x16x32_bf16(ah[rb], bh[c][s], acc[rb][c], 0, 0, 0);
      #pragma unroll
      for (int rb = 0; rb < 4; ++rb)
        acc[rb][c] = __builtin_amdgcn_mfma_f32_16x16x32_bf16(alr[rb], bh[c][s], acc[rb][c], 0, 0, 0);
      #pragma unroll
      for (int rb = 0; rb < 4; ++rb)
        acc[rb][c] = __builtin_amdgcn_mfma_f32_16x16x32_bf16(ah[rb], bl[c][s], acc[rb][c], 0, 0, 0);
    }
  }

  // ---- Epilogue: store feat + fused el/er ----
  int rquad = q * 4;
  #pragma unroll
  for (int c = 0; c < 2; ++c) {
    int h = wid * 2 + c;
    float alv = gal[h * 16 + colL];
    float arv = gar[h * 16 + colL];
    int col = wid * 32 + c * 16 + colL;
    #pragma unroll
    for (int rb = 0; rb < 4; ++rb) {
      f32x4 a = acc[rb][c];
      int row0g = blockRow0 + rb * 16 + rquad;
      #pragma unroll
      for (int r = 0; r < 4; ++r)
        Out[(size_t)(row0g + r) * kH + col] = a[r];
      float e0 = a[0] * alv, e1 = a[1] * alv, e2 = a[2] * alv, e3 = a[3] * alv;
      float f0 = a[0] * arv, f1 = a[1] * arv, f2 = a[2] * arv, f3 = a[3] * arv;
      #pragma unroll
      for (int m = 1; m < 16; m <<= 1) {
        e0 += __shfl_xor(e0, m, 64); e1 += __shfl_xor(e1, m, 64);
        e2 += __shfl_xor(e2, m, 64); e3 += __shfl_xor(e3, m, 64);
        f0 += __shfl_xor(f0, m, 64); f1 += __shfl_xor(f1, m, 64);
        f2 += __shfl_xor(f2, m, 64); f3 += __shfl_xor(f3, m, 64);
      }
      if (colL == 0) {
        elp[(size_t)(row0g + 0) * 8 + h] = e0;
        elp[(size_t)(row0g + 1) * 8 + h] = e1;
        elp[(size_t)(row0g + 2) * 8 + h] = e2;
        elp[(size_t)(row0g + 3) * 8 + h] = e3;
        erp[(size_t)(row0g + 0) * 8 + h] = f0;
        erp[(size_t)(row0g + 1) * 8 + h] = f1;
        erp[(size_t)(row0g + 2) * 8 + h] = f2;
        erp[(size_t)(row0g + 3) * 8 + h] = f3;
      }
    }
  }
}

// ---------------------------------------------------------------------------
// GAT layer-0 aggregation, wave per (b, v). Lane l owns dims [2l, 2l+1]:
// each edge's feat row is ONE coalesced 512-B wave read (4 lines/instr).
// out = elu(agg + bias). 8192 blocks; batch b -> XCD b.
// ---------------------------------------------------------------------------
__launch_bounds__(256)
__global__ void agg0_kernel(const float* __restrict__ feat, const float* __restrict__ el,
                            const float* __restrict__ er, const int* __restrict__ esrc,
                            const float* __restrict__ bias, float* __restrict__ outp) {
  int blk = blockIdx.x;                 // 8192 blocks; 1024 per batch
  int b = blk & 7;
  int grp = blk >> 3;                   // 0..1023
  int tid = threadIdx.x;
  int wave = tid >> 6, lane = tid & 63;
  int v = grp * 4 + wave;
  int t = v >> 10, n = v & 1023;
  int h = lane >> 3;
  int bv = (b << 12) + v;

  int srcs[10];
  int base8 = t * kEdgePerSnap + n * 8;
  #pragma unroll
  for (int k = 0; k < 8; ++k) srcs[k] = esrc[base8 + k];
  srcs[8] = esrc[t * kEdgePerSnap + kSelfOff + n];   // self loop (== v)
  float erv = er[bv * 8 + h];
  int ebase = b << 15;                  // b * 4096 * 8

  float e[10];
  float m = -1e30f;
  #pragma unroll
  for (int i = 0; i < 9; ++i) {
    float x = el[ebase + srcs[i] * 8 + h] + erv;
    x = x > 0.f ? x : kLRelu * x;
    e[i] = x;
    m = fmaxf(m, x);
  }
  if (t > 0) {                          // temporal edge (wave-uniform branch)
    int s9 = esrc[kTempBase + (t - 1) * kN + n];
    srcs[9] = s9;
    float x = el[ebase + s9 * 8 + h] + erv;
    x = x > 0.f ? x : kLRelu * x;
    e[9] = x;
    m = fmaxf(m, x);
  } else {
    srcs[9] = v;
    e[9] = -1e30f;
  }
  float s = 0.f;
  #pragma unroll
  for (int i = 0; i < 10; ++i) { e[i] = expf(e[i] - m); s += e[i]; }
  float inv = 1.0f / s;

  float ax = 0.f, ay = 0.f;
  size_t fbase = (size_t)(b << 12) * kH;
  #pragma unroll
  for (int i = 0; i < 10; ++i) {
    float w = e[i] * inv;
    float2 fv = *(const float2*)(feat + fbase + (size_t)srcs[i] * kH + lane * 2);
    ax += w * fv.x;
    ay += w * fv.y;
  }
  float2 bb = *(const float2*)(bias + lane * 2);
  float x0 = ax + bb.x, x1 = ay + bb.y;
  float2 o;
  o.x = x0 > 0.f ? x0 : expm1f(x0);
  o.y = x1 > 0.f ? x1 : expm1f(x1);
  *(float2*)(outp + (size_t)bv * kH + lane * 2) = o;
}

// ---------------------------------------------------------------------------
// Fused GAT layer-1 aggregation + residual + temporal attention + LN stats.
// Block = (b, n); wave t computes h[b,t,n,:] (agg + bias + residual), then
// in-block softmax over t pools into last[b,n,:]; per-block LN partials go
// to padded per-(b, n&15) stat lines. C is never materialized.
// ---------------------------------------------------------------------------
__launch_bounds__(256)
__global__ void agg1_attn(const float* __restrict__ feat, const float* __restrict__ el,
                          const float* __restrict__ er, const int* __restrict__ esrc,
                          const float* __restrict__ bias, const float* __restrict__ resid,
                          const float* __restrict__ q, float* __restrict__ last,
                          float* __restrict__ stats) {
  __shared__ float ssc[4];
  __shared__ float hbuf[4][128];
  __shared__ float sred[4];
  int blk = blockIdx.x;                 // 8192 blocks; 1024 per batch
  int b = blk & 7;
  int n = blk >> 3;                     // 0..1023
  int tid = threadIdx.x;
  int t = tid >> 6, lane = tid & 63;
  int v = (t << 10) + n;
  int h = lane >> 3;
  int bv = (b << 12) + v;

  // --- layer-1 aggregation ---
  int srcs[10];
  int base8 = t * kEdgePerSnap + n * 8;
  #pragma unroll
  for (int k = 0; k < 8; ++k) srcs[k] = esrc[base8 + k];
  srcs[8] = esrc[t * kEdgePerSnap + kSelfOff + n];
  float erv = er[bv * 8 + h];
  int ebase = b << 15;

  float e[10];
  float m = -1e30f;
  #pragma unroll
  for (int i = 0; i < 9; ++i) {
    float x = el[ebase + srcs[i] * 8 + h] + erv;
    x = x > 0.f ? x : kLRelu * x;
    e[i] = x;
    m = fmaxf(m, x);
  }
  if (t > 0) {
    int s9 = esrc[kTempBase + (t - 1) * kN + n];
    srcs[9] = s9;
    float x = el[ebase + s9 * 8 + h] + erv;
    x = x > 0.f ? x : kLRelu * x;
    e[9] = x;
    m = fmaxf(m, x);
  } else {
    srcs[9] = v;
    e[9] = -1e30f;
  }
  float s = 0.f;
  #pragma unroll
  for (int i = 0; i < 10; ++i) { e[i] = expf(e[i] - m); s += e[i]; }
  float inv = 1.0f / s;

  float ax = 0.f, ay = 0.f;
  size_t fbase = (size_t)(b << 12) * kH;
  #pragma unroll
  for (int i = 0; i < 10; ++i) {
    float w = e[i] * inv;
    float2 fv = *(const float2*)(feat + fbase + (size_t)srcs[i] * kH + lane * 2);
    ax += w * fv.x;
    ay += w * fv.y;
  }
  float2 bb = *(const float2*)(bias + lane * 2);
  float2 rv = *(const float2*)(resid + (size_t)bv * kH + lane * 2);
  float hx = ax + bb.x + rv.x;
  float hy = ay + bb.y + rv.y;

  // --- temporal attention over t ---
  float2 qv = *(const float2*)(q + (size_t)n * kH + lane * 2);
  float p = hx * qv.x + hy * qv.y;
  #pragma unroll
  for (int s_ = 1; s_ < 64; s_ <<= 1) p += __shfl_xor(p, s_, 64);
  if (lane == 0) ssc[t] = p;
  __syncthreads();
  float s0 = ssc[0], s1 = ssc[1], s2 = ssc[2], s3 = ssc[3];
  float mm = fmaxf(fmaxf(s0, s1), fmaxf(s2, s3));
  float a0 = expf(s0 - mm), a1 = expf(s1 - mm), a2 = expf(s2 - mm), a3 = expf(s3 - mm);
  float denom = 1.0f / (a0 + a1 + a2 + a3);
  float at = (t == 0 ? a0 : t == 1 ? a1 : t == 2 ? a2 : a3) * denom;
  hbuf[t][lane * 2]     = hx * at;
  hbuf[t][lane * 2 + 1] = hy * at;
  __syncthreads();

  // --- reduce over t, write last, LN partials ---
  float p1 = 0.f, p2 = 0.f;
  if (tid < 128) {
    int d = tid;
    float sum = hbuf[0][d] + hbuf[1][d] + hbuf[2][d] + hbuf[3][d];
    last[((size_t)(b * kN + n)) * kH + d] = sum;
    p1 = sum;
    p2 = sum * sum;
  }
  #pragma unroll
  for (int s_ = 1; s_ < 64; s_ <<= 1) {
    p1 += __shfl_xor(p1, s_, 64);
    p2 += __shfl_xor(p2, s_, 64);
  }
  if (tid < 128 && lane == 0) { sred[t * 2] = p1; sred[t * 2 + 1] = p2; }
  __syncthreads();
  if (tid == 0) {
    int slot = n & 15;
    atomicAdd(&stats[b * 256 + slot * 16],     sred[0] + sred[2]);
    atomicAdd(&stats[b * 256 + slot * 16 + 1], sred[1] + sred[3]);
  }
}

// ---------------------------------------------------------------------------
// Epilogue: out[b,s,n] = sum_h relu(LN(last)[b,n,h]*w1[s]+b1[s]) * w2[h] + b2
// One wave per (b, n).
// ---------------------------------------------------------------------------
__global__ void out_kernel(const float* __restrict__ last, const float* __restrict__ stats,
                           const float* __restrict__ w1, const float* __restrict__ b1,
                           const float* __restrict__ w2, const float* __restrict__ b2,
                           float* __restrict__ out) {
  int tid = threadIdx.x;
  int wave = tid >> 6, lane = tid & 63;
  int gw = blockIdx.x * 4 + wave;
  int b = gw >> 10, n = gw & 1023;
  float s1 = 0.f, s2 = 0.f;
  #pragma unroll
  for (int s = 0; s < 16; ++s) {
    s1 += stats[b * 256 + s * 16];
    s2 += stats[b * 256 + s * 16 + 1];
  }
  const float inv = 1.0f / (float)(kN * kH);
  float mu = s1 * inv;
  float var = s2 * inv - mu * mu;
  float scv = rsqrtf(var + 1e-5f);
  int d0 = lane * 2;
  float2 lv = *(const float2*)(last + ((size_t)(b * kN + n)) * kH + d0);
  float x0 = (lv.x - mu) * scv, x1 = (lv.y - mu) * scv;
  float w20 = w2[d0], w21 = w2[d0 + 1];
  float bias2 = b2[0];
  #pragma unroll
  for (int s = 0; s < kSeqOut; ++s) {
    float w1s = w1[s], b1s = b1[s];
    float v = fmaxf(x0 * w1s + b1s, 0.f) * w20 + fmaxf(x1 * w1s + b1s, 0.f) * w21;
    #pragma unroll
    for (int k = 1; k < 64; k <<= 1) v += __shfl_xor(v, k, 64);
    if (lane == 0) out[(size_t)(b * kSeqOut + s) * kN + n] = v + bias2;
  }
}

// ---------------------------------------------------------------------------
extern "C" void kernel_launch(void* const* d_in, const int* in_sizes, int n_in,
                              void* d_out, int out_size, void* d_ws, size_t ws_size,
                              hipStream_t stream) {
  const float* inputs   = (const float*)d_in[0];
  const float* W_in     = (const float*)d_in[1];
  const float* b_in     = (const float*)d_in[2];
  const float* spatial  = (const float*)d_in[3];
  const float* temporal = (const float*)d_in[4];
  const float* gw0      = (const float*)d_in[5];
  const float* gal0     = (const float*)d_in[6];
  const float* gar0     = (const float*)d_in[7];
  const float* gb0      = (const float*)d_in[8];
  const float* gw1      = (const float*)d_in[9];
  const float* gal1     = (const float*)d_in[10];
  const float* gar1     = (const float*)d_in[11];
  const float* gb1      = (const float*)d_in[12];
  const float* aggq     = (const float*)d_in[13];
  const float* w_out1   = (const float*)d_in[14];
  const float* b_out1   = (const float*)d_in[15];
  const float* w_out2   = (const float*)d_in[16];
  const float* b_out2   = (const float*)d_in[17];
  const int*   esrc     = (const int*)d_in[18];
  // d_in[19] = edge_dst (layout is static; unused)

  float* ws = (float*)d_ws;
  float* A     = ws;                 // (B,4,N,H)  window / residual   4,194,304
  float* Bf    = ws + 4194304;       // feat buffer                    4,194,304
  float* C     = ws + 8388608;       // layer-0 activations            4,194,304
  float* el    = ws + 12582912;      // (B*NT, 8)                        262,144
  float* er    = ws + 12845056;      //                                  262,144
  float* last  = ws + 13107200;      // (B,N,H)                        1,048,576
  float* stats = ws + 14155776;      // 5 iters x [8 b][16 slot][16]      10,240
  unsigned short* wsplit = (unsigned short*)(ws + 14166016);  // 2x(hi,lo) 128KB

  hipMemsetAsync(stats, 0, 5 * kStatsPerIter * sizeof(float), stream);
  prep_w<<<128, 256, 0, stream>>>(gw0, gw1, wsplit);
  const unsigned short* w0h = wsplit;
  const unsigned short* w0l = wsplit + 16384;
  const unsigned short* w1h = wsplit + 32768;
  const unsigned short* w1l = wsplit + 49152;

  const int lefts[5] = {0, 4, 7, 10, 13};
  for (int it = 0; it < 5; ++it) {
    const float* st_prev = (it == 0) ? stats : (stats + (it - 1) * kStatsPerIter);
    build_fs<<<4096, 256, 0, stream>>>(inputs, W_in, b_in, spatial, temporal,
                                       last, st_prev, A, lefts[it], it == 0 ? 1 : 0);
    // GAT layer 0 (GEMM + fused el/er), then aggregation
    gemm_mfma<<<kRows / 64, 256, 0, stream>>>(A, w0h, w0l, gal0, gar0, Bf, el, er);
    agg0_kernel<<<8192, 256, 0, stream>>>(Bf, el, er, esrc, gb0, C);
    // GAT layer 1 (GEMM + fused el/er), then fused agg+residual+attn+stats
    gemm_mfma<<<kRows / 64, 256, 0, stream>>>(C, w1h, w1l, gal1, gar1, Bf, el, er);
    agg1_attn<<<8192, 256, 0, stream>>>(Bf, el, er, esrc, gb1, A, aggq, last,
                                        stats + it * kStatsPerIter);
  }
  out_kernel<<<2048, 256, 0, stream>>>(last, stats + 4 * kStatsPerIter, w_out1, b_out1,
                                       w_out2, b_out2, (float*)d_out);
}